// Round 6
// baseline (145.134 us; speedup 1.0000x reference)
//
#include <hip/hip_runtime.h>

typedef _Float16 f16x8  __attribute__((ext_vector_type(8)));
typedef _Float16 h2v    __attribute__((ext_vector_type(2)));
typedef float    f32x16 __attribute__((ext_vector_type(16)));
typedef unsigned u32x16 __attribute__((ext_vector_type(16)));

#define NSTEP  42
#define NCHUNK 84

// ---------------------------------------------------------------------------
// Step tables (verified R2/R3): step s uses K-slots 0-7 (h=0, chunk A) and
// 8-15 (h=1, chunk B). Quadratic pairs share e0; multipliers x[da]/x[db] are
// the two halves of one packed half2 register (da even, db=da+1).
// ---------------------------------------------------------------------------
__host__ __device__ constexpr int stepDA(int s){
  return s < 4 ? 2*s : s < 12 ? 2*(s-4) : s < 24 ? 2*(s-12) : s < 40 ? 2*(s-24) : -1;
}
__host__ __device__ constexpr int stepDB(int s){
  return s < 40 ? stepDA(s) + 1 : -1;
}
__host__ __device__ constexpr int stepEA(int s){
  return s < 4 ? 0 : s < 12 ? 8 : s < 24 ? 16 : s < 40 ? 24 : (s == 40 ? 0 : 16);
}
__host__ __device__ constexpr int stepEB(int s){
  return s < 40 ? stepEA(s) : (s == 40 ? 8 : 24);
}

__device__ inline unsigned short f2h(float f){
  _Float16 h = (_Float16)f;
  unsigned short u; __builtin_memcpy(&u, &h, 2);
  return u;
}
__device__ inline unsigned pkmulh2(unsigned a, unsigned b){
  h2v x, y; __builtin_memcpy(&x, &a, 4); __builtin_memcpy(&y, &b, 4);
  h2v z = x * y;                        // v_pk_mul_f16
  unsigned r; __builtin_memcpy(&r, &z, 4);
  return r;
}
__device__ inline unsigned pkrtz(float lo, float hi){
  auto p = __builtin_amdgcn_cvt_pkrtz(lo, hi);   // __fp16 x2 vector
  unsigned u; __builtin_memcpy(&u, &p, 4);
  return u;
}

// ---------------------------------------------------------------------------
// Prep v5: one 64-lane wave per mixture, matrix in LDS, ROLLED loops
// (~2 KB code, no giant unroll, no scratch). Single-wave => LDS ops are in
// program order; zero barriers. t-loops split across the two 32-lane halves.
// Same math as the verified R3 prep.
// ---------------------------------------------------------------------------
__global__ __launch_bounds__(64) void gmm_prep(
    const float* __restrict__ mus, const float* __restrict__ sigmas,
    const float* __restrict__ phis, unsigned short* __restrict__ Bws,
    float* __restrict__ cstw)
{
  __shared__ float M[32 * 33];     // Sigma -> unscaled Cholesky -> L
  __shared__ float W[32 * 33];     // I -> L^-1 -> Sigma^-1
  __shared__ float dinv[32];       // 1/sqrt(d_j) = 1/L[j][j]
  __shared__ float dpiv[32];       // pivots d_j (for logdet)
  __shared__ float gv[32];         // Sigma^-1 mu
  __shared__ float mul[32];

  const int k    = blockIdx.x;
  const int lane = threadIdx.x;
  const int c    = lane & 31;      // column owned by this lane
  const int half = lane >> 5;      // t-range interleave

  // ---- load Sigma (coalesced), W = I, mu ----
  for (int i = lane; i < 1024; i += 64)
    M[(i >> 5) * 33 + (i & 31)] = sigmas[k * 1024 + i];
  for (int i = lane; i < 1024; i += 64)
    W[(i >> 5) * 33 + (i & 31)] = ((i >> 5) == (i & 31)) ? 1.f : 0.f;
  if (lane < 32) mul[lane] = mus[k * 32 + lane];

  // ---- Cholesky, outer-product form (unscaled columns; scale after) ----
  for (int j = 0; j < 32; ++j){
    float d    = M[j * 33 + j];          // broadcast read (updated first in
    float rs   = rsqrtf(d);              //  previous step's t-loop: t=j leads)
    float rinv = rs * rs;
    if (lane == 0){ dpiv[j] = d; dinv[j] = rs; }
    float mr = M[j * 33 + c] * rinv;     // row-j read, conflict-free
    if (c > j){
      for (int t = j + 1 + half; t < 32; t += 2)
        M[t * 33 + c] -= M[t * 33 + j] * mr;
    }
  }

  // ---- scale columns: M[i][j] *= dinv[j] (i>=j)  => M holds L ----
  for (int idx = lane; idx < 1024; idx += 64){
    int i = idx >> 5, j = idx & 31;
    if (i >= j) M[i * 33 + j] *= dinv[j];
  }

  // ---- forward solve L W = I  => W = L^-1 ----
  for (int i = 0; i < 32; ++i){
    float yi = W[i * 33 + c] * dinv[i];
    if (half == 0) W[i * 33 + c] = yi;
    for (int t = i + 1 + half; t < 32; t += 2)
      W[t * 33 + c] -= M[t * 33 + i] * yi;   // L[t][i] broadcast
  }

  // ---- backward solve L^T S = L^-1  => W = Sigma^-1 ----
  for (int i = 31; i >= 0; --i){
    float xi = W[i * 33 + c] * dinv[i];
    if (half == 0) W[i * 33 + c] = xi;
    for (int t = i - 1 - half; t >= 0; t -= 2)
      W[t * 33 + c] -= M[i * 33 + t] * xi;   // L^T[t][i] = L[i][t] broadcast
  }

  // ---- g = Sigma^-1 mu (column dot via symmetry), cst ----
  float hh = 0.f, ll = 0.f;
  if (lane < 32){
    float g = 0.f;
    for (int i = 0; i < 32; ++i) g += W[i * 33 + lane] * mul[i];
    gv[lane] = g;
    hh = mul[lane] * g;
    ll = logf(dpiv[lane]);
  }
  #pragma unroll
  for (int md = 1; md <= 16; md <<= 1){
    hh += __shfl_xor(hh, md);
    ll += __shfl_xor(ll, md);
  }
  if (lane == 0)
    cstw[k] = -logf(phis[k]) + 0.5f * (32.f * 1.8378770664093453f + ll) + 0.5f * hh;

  // ---- pack B coefficients (fp16), fragment-major: uint4 idx = ci*32 + k ----
  for (int ci = lane; ci < NCHUNK; ci += 64){
    int s2 = ci >> 1, hb = ci & 1;
    int d  = hb ? stepDB(s2) : stepDA(s2);
    int e0 = hb ? stepEB(s2) : stepEA(s2);
    unsigned short u8[8];
    for (int j = 0; j < 8; ++j){
      int e = e0 + j;
      float v;
      if (d < 0)       v = -gv[e];              // linear: coeff of x_e
      else if (e < d)  v = 0.f;                 // lower-tri pad
      else if (e == d) v = 0.5f * W[d * 33 + d];
      else             v = W[d * 33 + e];       // off-diag (0.5*2)
      u8[j] = f2h(v);
    }
    uint4 pk; __builtin_memcpy(&pk, u8, 16);
    ((uint4*)Bws)[ci * 32 + k] = pk;
  }
}

// ---------------------------------------------------------------------------
// Main (byte-identical to R5): template-unrolled steps, 512 threads = 8
// waves, 1 row-tile/wave, 256 rows/block, ~70 VGPR, 3 blocks/CU.
// ---------------------------------------------------------------------------
union AF8 { unsigned u[4]; f16x8 v; };

template<int S>
__device__ inline void gstep(const f16x8* __restrict__ Bf, int lane, int h,
                             unsigned sel, const u32x16& xu, f32x16& acc)
{
  f16x8 b = Bf[(S << 6) + lane];            // ds_read_b128, literal offset
  AF8 a;
  if constexpr (S < 40){
    constexpr int p = stepDA(S) >> 1;       // half2 reg holding (x[da],x[db])
    constexpr int e = stepEA(S) >> 1;
    unsigned m = __builtin_amdgcn_perm(xu[p], xu[p], sel);
    a.u[0] = pkmulh2(m, xu[e + 0]);
    a.u[1] = pkmulh2(m, xu[e + 1]);
    a.u[2] = pkmulh2(m, xu[e + 2]);
    a.u[3] = pkmulh2(m, xu[e + 3]);
  } else {
    constexpr int ea = stepEA(S) >> 1;
    constexpr int eb = stepEB(S) >> 1;
    a.u[0] = h ? xu[eb + 0] : xu[ea + 0];
    a.u[1] = h ? xu[eb + 1] : xu[ea + 1];
    a.u[2] = h ? xu[eb + 2] : xu[ea + 2];
    a.u[3] = h ? xu[eb + 3] : xu[ea + 3];
  }
  acc = __builtin_amdgcn_mfma_f32_32x32x16_f16(a.v, b, acc, 0, 0, 0);
}

template<int S>
__device__ inline void gsteps(const f16x8* __restrict__ Bf, int lane, int h,
                              unsigned sel, const u32x16& xu, f32x16& acc)
{
  if constexpr (S < NSTEP){
    gstep<S>(Bf, lane, h, sel, xu, acc);
    gsteps<S + 1>(Bf, lane, h, sel, xu, acc);
  }
}

__global__ __launch_bounds__(512, 4) void gmm_main(
    const float* __restrict__ X, const unsigned short* __restrict__ Bws,
    const float* __restrict__ cstg, float* __restrict__ out, int N)
{
  __shared__ uint4 ldsB[NSTEP * 64];   // 43008 B

  const int tid  = threadIdx.x;
  const int lane = tid & 63;
  const int wv   = tid >> 6;          // wave 0..7
  const int h    = lane >> 5;         // K-half
  const int c32  = lane & 31;         // A row in tile / C column (mixture)
  const int blockRow = blockIdx.x * 256;

  // stage B fragments (contiguous 43 KB)
  const uint4* Bg = (const uint4*)Bws;
  for (int i = tid; i < NSTEP * 64; i += 512) ldsB[i] = Bg[i];

  // byte-selector: duplicate low half (h=0) or high half (h=1) of a half2 reg
  const unsigned sel = h ? 0x03020302u : 0x01000100u;

  const int rowi = blockRow + wv * 32 + c32;
  const int rowc = rowi < N ? rowi : N - 1;

  u32x16 xu;
  {
    const float4* xp = (const float4*)(X + (size_t)rowc * 32);
    #pragma unroll
    for (int q = 0; q < 8; ++q){
      float4 v = xp[q];
      xu[q*2+0] = pkrtz(v.x, v.y);     // v_cvt_pkrtz_f16_f32
      xu[q*2+1] = pkrtz(v.z, v.w);
    }
  }
  const float cc = cstg[c32];
  __syncthreads();

  f32x16 acc;
  #pragma unroll
  for (int i = 0; i < 16; ++i) acc[i] = 0.f;

  gsteps<0>((const f16x8*)ldsB, lane, h, sel, xu, acc);

  // epilogue: +cst, 32-lane column max, divide, store
  float nll[16], mx[16];
  #pragma unroll
  for (int r = 0; r < 16; ++r){
    float nv = acc[r] + cc;
    nll[r] = nv; mx[r] = nv;
  }
  #pragma unroll
  for (int md = 1; md <= 16; md <<= 1){
    #pragma unroll
    for (int r = 0; r < 16; ++r)
      mx[r] = fmaxf(mx[r], __shfl_xor(mx[r], md));
  }
  const int rowBase = blockRow + wv * 32;
  #pragma unroll
  for (int r = 0; r < 16; ++r){
    int row = (r & 3) + 8 * (r >> 2) + 4 * h;   // verified C/D mapping
    int n = rowBase + row;
    if (n < N) out[(size_t)n * 32 + c32] = nll[r] * __builtin_amdgcn_rcpf(mx[r]);
  }
}

extern "C" void kernel_launch(void* const* d_in, const int* in_sizes, int n_in,
                              void* d_out, int out_size, void* d_ws, size_t ws_size,
                              hipStream_t stream)
{
  const float* X      = (const float*)d_in[0];
  const float* mus    = (const float*)d_in[1];
  const float* sigmas = (const float*)d_in[2];
  const float* phis   = (const float*)d_in[3];
  float* out = (float*)d_out;
  const int N = in_sizes[0] / 32;

  unsigned short* Bws = (unsigned short*)d_ws;
  float* cstw = (float*)((char*)d_ws + NCHUNK * 256 * 2);   // +43008 B

  gmm_prep<<<32, 64, 0, stream>>>(mus, sigmas, phis, Bws, cstw);

  const int nb = (N + 255) / 256;
  gmm_main<<<nb, 512, 0, stream>>>(X, Bws, cstw, out, N);
}

// Round 7
// 114.540 us; speedup vs baseline: 1.2671x; 1.2671x over previous
//
#include <hip/hip_runtime.h>

typedef _Float16 f16x8  __attribute__((ext_vector_type(8)));
typedef _Float16 h2v    __attribute__((ext_vector_type(2)));
typedef float    f32x16 __attribute__((ext_vector_type(16)));
typedef unsigned u32x16 __attribute__((ext_vector_type(16)));

#define NSTEP  42
#define NCHUNK 84
#define LSTR   36      // LDS row stride in floats: 144 B, 16B-aligned rows

// ---------------------------------------------------------------------------
// Step tables (verified R2-R6)
// ---------------------------------------------------------------------------
__host__ __device__ constexpr int stepDA(int s){
  return s < 4 ? 2*s : s < 12 ? 2*(s-4) : s < 24 ? 2*(s-12) : s < 40 ? 2*(s-24) : -1;
}
__host__ __device__ constexpr int stepDB(int s){
  return s < 40 ? stepDA(s) + 1 : -1;
}
__host__ __device__ constexpr int stepEA(int s){
  return s < 4 ? 0 : s < 12 ? 8 : s < 24 ? 16 : s < 40 ? 24 : (s == 40 ? 0 : 16);
}
__host__ __device__ constexpr int stepEB(int s){
  return s < 40 ? stepEA(s) : (s == 40 ? 8 : 24);
}

__device__ inline unsigned short f2h(float f){
  _Float16 h = (_Float16)f;
  unsigned short u; __builtin_memcpy(&u, &h, 2);
  return u;
}
__device__ inline unsigned pkmulh2(unsigned a, unsigned b){
  h2v x, y; __builtin_memcpy(&x, &a, 4); __builtin_memcpy(&y, &b, 4);
  h2v z = x * y;
  unsigned r; __builtin_memcpy(&r, &z, 4);
  return r;
}
__device__ inline unsigned pkrtz(float lo, float hi){
  auto p = __builtin_amdgcn_cvt_pkrtz(lo, hi);
  unsigned u; __builtin_memcpy(&u, &p, 4);
  return u;
}
__device__ inline float dot4(float4 a, float4 b){
  return a.x*b.x + a.y*b.y + a.z*b.z + a.w*b.w;
}

// ---------------------------------------------------------------------------
// 32x32 matmul on 256 threads: C = A*B  (or C = 2*X - A*B when X != nullptr).
// Thread (c = tid&31, rows r0..r0+3). All LDS access conflict-free/broadcast;
// no loop-carried LDS dependence -> fully pipelined. Caller barriers.
// ---------------------------------------------------------------------------
__device__ inline void mm32(float* __restrict__ C, const float* __restrict__ A,
                            const float* __restrict__ B, const float* __restrict__ X,
                            int tid)
{
  const int c  = tid & 31;
  const int r0 = (tid >> 5) * 4;
  float a0 = 0.f, a1 = 0.f, a2 = 0.f, a3 = 0.f;
  #pragma unroll
  for (int kb = 0; kb < 8; ++kb){
    float b0 = B[(kb*4+0)*LSTR + c];
    float b1 = B[(kb*4+1)*LSTR + c];
    float b2 = B[(kb*4+2)*LSTR + c];
    float b3 = B[(kb*4+3)*LSTR + c];
    float4 v0 = *(const float4*)&A[(r0+0)*LSTR + kb*4];
    float4 v1 = *(const float4*)&A[(r0+1)*LSTR + kb*4];
    float4 v2 = *(const float4*)&A[(r0+2)*LSTR + kb*4];
    float4 v3 = *(const float4*)&A[(r0+3)*LSTR + kb*4];
    a0 += v0.x*b0 + v0.y*b1 + v0.z*b2 + v0.w*b3;
    a1 += v1.x*b0 + v1.y*b1 + v1.z*b2 + v1.w*b3;
    a2 += v2.x*b0 + v2.y*b1 + v2.z*b2 + v2.w*b3;
    a3 += v3.x*b0 + v3.y*b1 + v3.z*b2 + v3.w*b3;
  }
  if (X){
    C[(r0+0)*LSTR + c] = 2.f*X[(r0+0)*LSTR + c] - a0;
    C[(r0+1)*LSTR + c] = 2.f*X[(r0+1)*LSTR + c] - a1;
    C[(r0+2)*LSTR + c] = 2.f*X[(r0+2)*LSTR + c] - a2;
    C[(r0+3)*LSTR + c] = 2.f*X[(r0+3)*LSTR + c] - a3;
  } else {
    C[(r0+0)*LSTR + c] = a0;
    C[(r0+1)*LSTR + c] = a1;
    C[(r0+2)*LSTR + c] = a2;
    C[(r0+3)*LSTR + c] = a3;
  }
}

// ---------------------------------------------------------------------------
// Prep v6: Newton-Schulz inversion + trace-series logdet. One block (256 thr)
// per mixture. All heavy stages are parallel matmuls; no serial chains.
//   Sigma = I + A*A^T  =>  lambda_min >= 1 (used for both brackets).
// ---------------------------------------------------------------------------
__global__ __launch_bounds__(256) void gmm_prep(
    const float* __restrict__ mus, const float* __restrict__ sigmas,
    const float* __restrict__ phis, unsigned short* __restrict__ Bws,
    float* __restrict__ cstw)
{
  __shared__ alignas(16) float Sm[32*LSTR];   // Sigma -> later P3
  __shared__ alignas(16) float Xa[32*LSTR];   // NS ping -> later P2
  __shared__ alignas(16) float Xb[32*LSTR];   // NS pong (final X ends here)
  __shared__ alignas(16) float Ym[32*LSTR];   // S*X product -> P -> P4
  __shared__ alignas(16) float mul[32];
  __shared__ float vv[32];                    // power-iteration vector
  __shared__ float gld[32];                   // Sigma^-1 mu
  __shared__ float tsum[12];                  // t1..t3 diags, b, cL
  __shared__ float red[32];                   // cross-wave dot reduction

  const int k   = blockIdx.x;
  const int tid = threadIdx.x;

  // ---- load Sigma (coalesced), mu ----
  for (int i = tid; i < 1024; i += 256)
    Sm[(i >> 5) * LSTR + (i & 31)] = sigmas[k * 1024 + i];
  if (tid < 32) mul[tid] = mus[k * 32 + tid];
  if (tid == 0) vv[0] = 0.f;   // touch
  __syncthreads();

  // ---- power iteration for lambda_max (wave 0 only, in-order LDS) ----
  if (tid < 64){
    const int c = tid & 31;
    if (tid < 32) vv[c] = 1.f;
    float lam = 2.f;
    for (int it = 0; it < 12; ++it){
      float u = 0.f;
      #pragma unroll
      for (int jb = 0; jb < 8; ++jb){
        float4 sr = *(const float4*)&Sm[c * LSTR + jb * 4];
        float4 vj = *(const float4*)&vv[jb * 4];
        u += dot4(sr, vj);
      }
      float vc  = vv[c];
      float num = vc * u, den = vc * vc, mx = fabsf(u);
      #pragma unroll
      for (int md = 1; md <= 16; md <<= 1){
        num += __shfl_xor(num, md);
        den += __shfl_xor(den, md);
        mx   = fmaxf(mx, __shfl_xor(mx, md));
      }
      lam = num / den;
      if (tid < 32) vv[c] = u / mx;
    }
    if (tid == 0){
      tsum[9]  = 1.f / (1.08f * lam);          // c0 for NS start
      tsum[10] = 2.f / (1.f + 1.02f * lam);    // cL for logdet series
    }
  }
  __syncthreads();

  const float c0 = tsum[9];
  const float cL = tsum[10];

  // ---- X1 = c0*(2I - c0*S), elementwise (exact first NS step) ----
  for (int i = tid; i < 1024; i += 256){
    int r = i >> 5, cc = i & 31;
    Xa[r * LSTR + cc] = (r == cc ? 2.f * c0 : 0.f) - c0 * c0 * Sm[r * LSTR + cc];
  }

  // ---- 5 Newton-Schulz steps: X <- 2X - X*(S*X) ----
  float* Xc = Xa;
  float* Xn = Xb;
  for (int it = 0; it < 5; ++it){
    __syncthreads();
    mm32(Ym, Sm, Xc, nullptr, tid);    // Y = S*X
    __syncthreads();
    mm32(Xn, Xc, Ym, Xc, tid);         // X' = 2X - X*Y
    float* t = Xc; Xc = Xn; Xn = t;
  }
  // final X in Xc (= Xb after 5 swaps); Xn (= Xa) is free scratch
  __syncthreads();

  // ---- P = cL*S - I  -> Ym ----
  for (int i = tid; i < 1024; i += 256){
    int r = i >> 5, cc = i & 31;
    Ym[r * LSTR + cc] = cL * Sm[r * LSTR + cc] - (r == cc ? 1.f : 0.f);
  }
  __syncthreads();
  if (tid < 64){                       // t1 = tr(P)
    float v = Ym[(tid & 31) * LSTR + (tid & 31)];
    #pragma unroll
    for (int md = 1; md <= 16; md <<= 1) v += __shfl_xor(v, md);
    if (tid == 0) tsum[1] = v;
  }
  __syncthreads();
  mm32(Xn, Ym, Ym, nullptr, tid);      // P2 = P*P -> Xn(Xa)
  __syncthreads();
  if (tid < 64){                       // t2 = tr(P2)
    float v = Xn[(tid & 31) * LSTR + (tid & 31)];
    #pragma unroll
    for (int md = 1; md <= 16; md <<= 1) v += __shfl_xor(v, md);
    if (tid == 0) tsum[2] = v;
  }
  __syncthreads();
  mm32(Sm, Xn, Ym, nullptr, tid);      // P3 = P2*P -> Sm (S no longer needed)
  __syncthreads();
  if (tid < 64){                       // t3 = tr(P3)
    float v = Sm[(tid & 31) * LSTR + (tid & 31)];
    #pragma unroll
    for (int md = 1; md <= 16; md <<= 1) v += __shfl_xor(v, md);
    if (tid == 0) tsum[3] = v;
  }
  __syncthreads();
  mm32(Ym, Xn, Xn, nullptr, tid);      // P4 = P2*P2 -> Ym (t1 already taken)
  __syncthreads();

  // ---- t4..t8 via elementwise dots (all powers symmetric) ----
  {
    int i  = tid >> 3;
    int j0 = (tid & 7) * 4;
    float4 p2 = *(const float4*)&Xn[i * LSTR + j0];
    float4 p3 = *(const float4*)&Sm[i * LSTR + j0];
    float4 p4 = *(const float4*)&Ym[i * LSTR + j0];
    float d4 = dot4(p2, p2);   // tr(P^4)
    float d5 = dot4(p2, p3);   // tr(P^5)
    float d6 = dot4(p3, p3);   // tr(P^6)
    float d7 = dot4(p4, p3);   // tr(P^7)
    float d8 = dot4(p4, p4);   // tr(P^8)
    #pragma unroll
    for (int md = 1; md <= 32; md <<= 1){
      d4 += __shfl_xor(d4, md); d5 += __shfl_xor(d5, md);
      d6 += __shfl_xor(d6, md); d7 += __shfl_xor(d7, md);
      d8 += __shfl_xor(d8, md);
    }
    if ((tid & 63) == 0){
      int w = tid >> 6;
      red[w*8+0] = d4; red[w*8+1] = d5; red[w*8+2] = d6;
      red[w*8+3] = d7; red[w*8+4] = d8;
    }
  }
  __syncthreads();

  // ---- g = X*mu, hh = mu.g, cst (wave 0) ----
  if (tid < 64){
    const int c = tid & 31;
    float g = 0.f;
    #pragma unroll
    for (int jb = 0; jb < 8; ++jb){
      float4 xr = *(const float4*)&Xc[c * LSTR + jb * 4];
      float4 mv = *(const float4*)&mul[jb * 4];
      g += dot4(xr, mv);
    }
    if (tid < 32) gld[c] = g;
    float hh = mul[c] * g;
    #pragma unroll
    for (int md = 1; md <= 16; md <<= 1) hh += __shfl_xor(hh, md);
    if (tid == 0){
      float t4 = red[0] + red[8] + red[16] + red[24];
      float t5 = red[1] + red[9] + red[17] + red[25];
      float t6 = red[2] + red[10] + red[18] + red[26];
      float t7 = red[3] + red[11] + red[19] + red[27];
      float t8 = red[4] + red[12] + red[20] + red[28];
      float t1 = tsum[1], t2 = tsum[2], t3 = tsum[3];
      float ldc = t1 - t2*0.5f + t3*(1.f/3.f) - t4*0.25f
                + t5*0.2f - t6*(1.f/6.f) + t7*(1.f/7.f) - t8*0.125f;
      float logdet = ldc - 32.f * logf(cL);
      cstw[k] = -logf(phis[k]) + 0.5f * (32.f * 1.8378770664093453f + logdet) + 0.5f * hh;
    }
  }
  __syncthreads();

  // ---- pack B coefficients (fp16), fragment-major: uint4 idx = ci*32 + k ----
  if (tid < NCHUNK){
    int s2 = tid >> 1, hb = tid & 1;
    int d  = hb ? stepDB(s2) : stepDA(s2);
    int e0 = hb ? stepEB(s2) : stepEA(s2);
    unsigned short u8[8];
    for (int j = 0; j < 8; ++j){
      int e = e0 + j;
      float v;
      if (d < 0)       v = -gld[e];
      else if (e < d)  v = 0.f;
      else if (e == d) v = 0.5f * Xc[d * LSTR + d];
      else             v = Xc[d * LSTR + e];
      u8[j] = f2h(v);
    }
    uint4 pk; __builtin_memcpy(&pk, u8, 16);
    ((uint4*)Bws)[tid * 32 + k] = pk;
  }
}

// ---------------------------------------------------------------------------
// Main (byte-identical to R5): template-unrolled steps, 512 threads = 8
// waves, 1 row-tile/wave, 256 rows/block, ~70 VGPR, 3 blocks/CU.
// ---------------------------------------------------------------------------
union AF8 { unsigned u[4]; f16x8 v; };

template<int S>
__device__ inline void gstep(const f16x8* __restrict__ Bf, int lane, int h,
                             unsigned sel, const u32x16& xu, f32x16& acc)
{
  f16x8 b = Bf[(S << 6) + lane];
  AF8 a;
  if constexpr (S < 40){
    constexpr int p = stepDA(S) >> 1;
    constexpr int e = stepEA(S) >> 1;
    unsigned m = __builtin_amdgcn_perm(xu[p], xu[p], sel);
    a.u[0] = pkmulh2(m, xu[e + 0]);
    a.u[1] = pkmulh2(m, xu[e + 1]);
    a.u[2] = pkmulh2(m, xu[e + 2]);
    a.u[3] = pkmulh2(m, xu[e + 3]);
  } else {
    constexpr int ea = stepEA(S) >> 1;
    constexpr int eb = stepEB(S) >> 1;
    a.u[0] = h ? xu[eb + 0] : xu[ea + 0];
    a.u[1] = h ? xu[eb + 1] : xu[ea + 1];
    a.u[2] = h ? xu[eb + 2] : xu[ea + 2];
    a.u[3] = h ? xu[eb + 3] : xu[ea + 3];
  }
  acc = __builtin_amdgcn_mfma_f32_32x32x16_f16(a.v, b, acc, 0, 0, 0);
}

template<int S>
__device__ inline void gsteps(const f16x8* __restrict__ Bf, int lane, int h,
                              unsigned sel, const u32x16& xu, f32x16& acc)
{
  if constexpr (S < NSTEP){
    gstep<S>(Bf, lane, h, sel, xu, acc);
    gsteps<S + 1>(Bf, lane, h, sel, xu, acc);
  }
}

__global__ __launch_bounds__(512, 4) void gmm_main(
    const float* __restrict__ X, const unsigned short* __restrict__ Bws,
    const float* __restrict__ cstg, float* __restrict__ out, int N)
{
  __shared__ uint4 ldsB[NSTEP * 64];   // 43008 B

  const int tid  = threadIdx.x;
  const int lane = tid & 63;
  const int wv   = tid >> 6;
  const int h    = lane >> 5;
  const int c32  = lane & 31;
  const int blockRow = blockIdx.x * 256;

  const uint4* Bg = (const uint4*)Bws;
  for (int i = tid; i < NSTEP * 64; i += 512) ldsB[i] = Bg[i];

  const unsigned sel = h ? 0x03020302u : 0x01000100u;

  const int rowi = blockRow + wv * 32 + c32;
  const int rowc = rowi < N ? rowi : N - 1;

  u32x16 xu;
  {
    const float4* xp = (const float4*)(X + (size_t)rowc * 32);
    #pragma unroll
    for (int q = 0; q < 8; ++q){
      float4 v = xp[q];
      xu[q*2+0] = pkrtz(v.x, v.y);
      xu[q*2+1] = pkrtz(v.z, v.w);
    }
  }
  const float cc = cstg[c32];
  __syncthreads();

  f32x16 acc;
  #pragma unroll
  for (int i = 0; i < 16; ++i) acc[i] = 0.f;

  gsteps<0>((const f16x8*)ldsB, lane, h, sel, xu, acc);

  float nll[16], mx[16];
  #pragma unroll
  for (int r = 0; r < 16; ++r){
    float nv = acc[r] + cc;
    nll[r] = nv; mx[r] = nv;
  }
  #pragma unroll
  for (int md = 1; md <= 16; md <<= 1){
    #pragma unroll
    for (int r = 0; r < 16; ++r)
      mx[r] = fmaxf(mx[r], __shfl_xor(mx[r], md));
  }
  const int rowBase = blockRow + wv * 32;
  #pragma unroll
  for (int r = 0; r < 16; ++r){
    int row = (r & 3) + 8 * (r >> 2) + 4 * h;
    int n = rowBase + row;
    if (n < N) out[(size_t)n * 32 + c32] = nll[r] * __builtin_amdgcn_rcpf(mx[r]);
  }
}

extern "C" void kernel_launch(void* const* d_in, const int* in_sizes, int n_in,
                              void* d_out, int out_size, void* d_ws, size_t ws_size,
                              hipStream_t stream)
{
  const float* X      = (const float*)d_in[0];
  const float* mus    = (const float*)d_in[1];
  const float* sigmas = (const float*)d_in[2];
  const float* phis   = (const float*)d_in[3];
  float* out = (float*)d_out;
  const int N = in_sizes[0] / 32;

  unsigned short* Bws = (unsigned short*)d_ws;
  float* cstw = (float*)((char*)d_ws + NCHUNK * 256 * 2);   // +43008 B

  gmm_prep<<<32, 256, 0, stream>>>(mus, sigmas, phis, Bws, cstw);

  const int nb = (N + 255) / 256;
  gmm_main<<<nb, 512, 0, stream>>>(X, Bws, cstw, out, N);
}

// Round 8
// 105.237 us; speedup vs baseline: 1.3791x; 1.0884x over previous
//
#include <hip/hip_runtime.h>

typedef _Float16 f16x8  __attribute__((ext_vector_type(8)));
typedef _Float16 h2v    __attribute__((ext_vector_type(2)));
typedef float    f32x16 __attribute__((ext_vector_type(16)));
typedef unsigned u32x16 __attribute__((ext_vector_type(16)));

#define NSTEP  42
#define NCHUNK 84
#define PSTR   36      // prep LDS row stride (floats): 144B rows, b128-aligned

// ---------------------------------------------------------------------------
// Step tables (verified R2-R7)
// ---------------------------------------------------------------------------
__host__ __device__ constexpr int stepDA(int s){
  return s < 4 ? 2*s : s < 12 ? 2*(s-4) : s < 24 ? 2*(s-12) : s < 40 ? 2*(s-24) : -1;
}
__host__ __device__ constexpr int stepDB(int s){
  return s < 40 ? stepDA(s) + 1 : -1;
}
__host__ __device__ constexpr int stepEA(int s){
  return s < 4 ? 0 : s < 12 ? 8 : s < 24 ? 16 : s < 40 ? 24 : (s == 40 ? 0 : 16);
}
__host__ __device__ constexpr int stepEB(int s){
  return s < 40 ? stepEA(s) : (s == 40 ? 8 : 24);
}

__device__ inline unsigned short f2h(float f){
  _Float16 h = (_Float16)f;
  unsigned short u; __builtin_memcpy(&u, &h, 2);
  return u;
}
__device__ inline unsigned pkmulh2(unsigned a, unsigned b){
  h2v x, y; __builtin_memcpy(&x, &a, 4); __builtin_memcpy(&y, &b, 4);
  h2v z = x * y;
  unsigned r; __builtin_memcpy(&r, &z, 4);
  return r;
}
__device__ inline unsigned pkrtz(float lo, float hi){
  auto p = __builtin_amdgcn_cvt_pkrtz(lo, hi);
  unsigned u; __builtin_memcpy(&u, &p, 4);
  return u;
}
__device__ inline float dot4(float4 a, float4 b){
  return a.x*b.x + a.y*b.y + a.z*b.z + a.w*b.w;
}

// Build B-fragments (k 0..15 -> b1, k 16..31 -> b2) for a symmetric matrix
// held in verified C-layout regs (col=lane&31, row=(r&3)+8*(r>>2)+4*h).
// Lane (h,c) needs col-c rows h*8+j (b1) and 16+h*8+j (b2); missing rows live
// in the cross-half partner lane -> shfl_xor(32).
__device__ inline void bfrags(const f32x16& s, int h, f16x8& b1, f16x8& b2){
  float xo[16];
  #pragma unroll
  for (int j = 0; j < 16; ++j) xo[j] = __shfl_xor(s[j], 32);
  unsigned u[8];
  float e[8];
  #pragma unroll
  for (int j = 0; j < 4; ++j){
    e[j]   = h ? xo[4+j] : s[j];      // rows 8h+0..3
    e[4+j] = h ? s[4+j]  : xo[j];     // rows 8h+4..7
  }
  u[0] = pkrtz(e[0],e[1]); u[1] = pkrtz(e[2],e[3]);
  u[2] = pkrtz(e[4],e[5]); u[3] = pkrtz(e[6],e[7]);
  #pragma unroll
  for (int j = 0; j < 4; ++j){
    e[j]   = h ? xo[12+j] : s[8+j];   // rows 16+8h+0..3
    e[4+j] = h ? s[12+j]  : xo[8+j];  // rows 16+8h+4..7
  }
  u[4] = pkrtz(e[0],e[1]); u[5] = pkrtz(e[2],e[3]);
  u[6] = pkrtz(e[4],e[5]); u[7] = pkrtz(e[6],e[7]);
  __builtin_memcpy(&b1, &u[0], 16);
  __builtin_memcpy(&b2, &u[4], 16);
}

// A-fragments for matrix in LDS (row-major, PSTR stride): lane row = c.
__device__ inline void afrags(const float* Ml, int c, int h, f16x8& a1, f16x8& a2){
  unsigned u[8];
  #pragma unroll
  for (int jj = 0; jj < 4; ++jj){
    float2 v1 = *(const float2*)&Ml[c*PSTR + h*8 + 2*jj];
    float2 v2 = *(const float2*)&Ml[c*PSTR + 16 + h*8 + 2*jj];
    u[jj]   = pkrtz(v1.x, v1.y);
    u[4+jj] = pkrtz(v2.x, v2.y);
  }
  __builtin_memcpy(&a1, &u[0], 16);
  __builtin_memcpy(&a2, &u[4], 16);
}

// ---------------------------------------------------------------------------
// Prep v7: one wave per mixture, MFMA Newton-Schulz, zero barriers.
//  c = 1/Gershgorin(S); X1 = c(2I-cS); 5x { Y=SX; R=I-Y; X+=X*R }.
//  logdet via tau_j = tr(R0^j) from stored R-regs (R_{n+1}=R_n^2 telescoping).
// ---------------------------------------------------------------------------
__global__ __launch_bounds__(64) void gmm_prep(
    const float* __restrict__ mus, const float* __restrict__ sigmas,
    const float* __restrict__ phis, unsigned short* __restrict__ Bws,
    float* __restrict__ cstw)
{
  __shared__ alignas(16) float Sl[32*PSTR];   // Sigma (fp32)
  __shared__ alignas(16) float Xl[32*PSTR];   // current X (fp32)
  __shared__ float gld[32];

  const int k    = blockIdx.x;
  const int lane = threadIdx.x;
  const int c    = lane & 31;
  const int h    = lane >> 5;

  // ---- load Sigma (coalesced float4) ----
  {
    const float4* sg = (const float4*)(sigmas + (size_t)k * 1024);
    #pragma unroll
    for (int q = 0; q < 4; ++q){
      int idx = lane + 64*q;            // float4 index
      float4 v = sg[idx];
      int r  = idx >> 3;
      int c0 = (idx & 7) * 4;
      *(float4*)&Sl[r*PSTR + c0] = v;
    }
  }

  // ---- Gershgorin bound: G = max_r sum_c |S[r][c]|  (row r = c per lane) ----
  float rs = 0.f;
  #pragma unroll
  for (int q = 0; q < 8; ++q){
    float4 v = *(const float4*)&Sl[c*PSTR + q*4];
    rs += fabsf(v.x) + fabsf(v.y) + fabsf(v.z) + fabsf(v.w);
  }
  #pragma unroll
  for (int md = 1; md <= 16; md <<= 1)
    rs = fmaxf(rs, __shfl_xor(rs, md));
  const float cg = 1.f / rs;

  // ---- S A-fragments (static across iterations) ----
  f16x8 sA1, sA2;
  afrags(Sl, c, h, sA1, sA2);

  // ---- X1 = cg*(2I - cg*S) and R0 = I - cg*S, in C-layout regs ----
  f32x16 Xc, R0;
  float p1 = 0.f;                        // tr(R0) partial
  float p2 = 0.f;                        // <R0,R0>
  #pragma unroll
  for (int r = 0; r < 16; ++r){
    int row  = (r & 3) + 8 * (r >> 2) + 4 * h;
    float sv = Sl[row*PSTR + c];
    float iv = (row == c) ? 1.f : 0.f;
    float r0 = iv - cg * sv;
    R0[r] = r0;
    Xc[r] = cg * (2.f * iv - cg * sv);
    p1 += (row == c) ? r0 : 0.f;
    p2 += r0 * r0;
    Xl[row*PSTR + c] = Xc[r];
  }

  // ---- 5 Newton-Schulz iterations, tau bookkeeping ----
  f32x16 R1, R2, R3;
  float p3 = 0.f, p4 = 0.f, p5 = 0.f, p6 = 0.f, p8 = 0.f;
  float p9 = 0.f, p10 = 0.f, p12 = 0.f, p16 = 0.f;

  #pragma unroll
  for (int it = 0; it < 5; ++it){
    // Y = S * X
    f16x8 xb1, xb2;
    bfrags(Xc, h, xb1, xb2);
    f32x16 Yc;
    #pragma unroll
    for (int i = 0; i < 16; ++i) Yc[i] = 0.f;
    Yc = __builtin_amdgcn_mfma_f32_32x32x16_f16(sA1, xb1, Yc, 0, 0, 0);
    Yc = __builtin_amdgcn_mfma_f32_32x32x16_f16(sA2, xb2, Yc, 0, 0, 0);

    // R = I - Y
    f32x16 Rc;
    #pragma unroll
    for (int r = 0; r < 16; ++r){
      int row = (r & 3) + 8 * (r >> 2) + 4 * h;
      Rc[r] = ((row == c) ? 1.f : 0.f) - Yc[r];
    }

    if (it == 0){
      #pragma unroll
      for (int r = 0; r < 16; ++r){ p3 += R0[r]*Rc[r]; p4 += Rc[r]*Rc[r]; }
      R1 = Rc;
    } else if (it == 1){
      #pragma unroll
      for (int r = 0; r < 16; ++r){ p5 += R0[r]*Rc[r]; p6 += R1[r]*Rc[r]; p8 += Rc[r]*Rc[r]; }
      R2 = Rc;
    } else if (it == 2){
      #pragma unroll
      for (int r = 0; r < 16; ++r){
        p9 += R0[r]*Rc[r]; p10 += R1[r]*Rc[r]; p12 += R2[r]*Rc[r]; p16 += Rc[r]*Rc[r];
      }
      R3 = Rc;
    }
    (void)R3;

    // X' = X + X*R
    f16x8 xa1, xa2, rb1, rb2;
    afrags(Xl, c, h, xa1, xa2);
    bfrags(Rc, h, rb1, rb2);
    f32x16 Xn = Xc;
    Xn = __builtin_amdgcn_mfma_f32_32x32x16_f16(xa1, rb1, Xn, 0, 0, 0);
    Xn = __builtin_amdgcn_mfma_f32_32x32x16_f16(xa2, rb2, Xn, 0, 0, 0);
    #pragma unroll
    for (int r = 0; r < 16; ++r){
      int row = (r & 3) + 8 * (r >> 2) + 4 * h;
      Xl[row*PSTR + c] = Xn[r];
    }
    Xc = Xn;
  }

  // ---- reduce tau partials over all 64 lanes ----
  float pp[11] = {p1,p2,p3,p4,p5,p6,p8,p9,p10,p12,p16};
  #pragma unroll
  for (int i = 0; i < 11; ++i){
    float v = pp[i];
    #pragma unroll
    for (int md = 1; md <= 32; md <<= 1) v += __shfl_xor(v, md);
    pp[i] = v;
  }
  const float t1 = pp[0], t2 = pp[1], t3 = pp[2], t4 = pp[3], t5 = pp[4];
  const float t6 = pp[5], t8 = pp[6], t9 = pp[7], t10 = pp[8], t12 = pp[9];

  // ---- g = X*mu (row c of symmetric X), hh = mu.g ----
  const float4* mp = (const float4*)(mus + (size_t)k * 32);
  float g = 0.f;
  #pragma unroll
  for (int q = 0; q < 8; ++q)
    g += dot4(*(const float4*)&Xl[c*PSTR + q*4], mp[q]);
  if (h == 0) gld[c] = g;
  float hh = g * mus[(size_t)k * 32 + c];
  #pragma unroll
  for (int md = 1; md <= 16; md <<= 1) hh += __shfl_xor(hh, md);

  // ---- logdet(S) = -(sum tau_j/j) - 32*log(cg) ; cst ----
  if (lane == 0){
    float t7  = sqrtf(fmaxf(t6 * t8, 0.f));
    float t11 = sqrtf(fmaxf(t10 * t12, 0.f));
    float rg  = (t10 > 1e-30f) ? sqrtf(t12 / t10) : 0.f;
    rg = fminf(rg, 0.95f);
    float tail = t12 * rg / (13.f * (1.f - rg));
    float ser = t1 + t2*0.5f + t3*(1.f/3.f) + t4*0.25f + t5*0.2f
              + t6*(1.f/6.f) + t7*(1.f/7.f) + t8*0.125f + t9*(1.f/9.f)
              + t10*0.1f + t11*(1.f/11.f) + t12*(1.f/12.f) + tail;
    float logdet = -ser - 32.f * logf(cg);
    cstw[k] = -logf(phis[k]) + 0.5f * (32.f * 1.8378770664093453f + logdet) + 0.5f * hh;
  }

  // ---- pack B coefficients (fp16), fragment-major: uint4 idx = ci*32 + k ----
  for (int ci = lane; ci < NCHUNK; ci += 64){
    int s2 = ci >> 1, hb = ci & 1;
    int d  = hb ? stepDB(s2) : stepDA(s2);
    int e0 = hb ? stepEB(s2) : stepEA(s2);
    unsigned short u8[8];
    for (int j = 0; j < 8; ++j){
      int e = e0 + j;
      float v;
      if (d < 0)       v = -gld[e];
      else if (e < d)  v = 0.f;
      else if (e == d) v = 0.5f * Xl[d*PSTR + d];
      else             v = Xl[d*PSTR + e];
      u8[j] = f2h(v);
    }
    uint4 pk; __builtin_memcpy(&pk, u8, 16);
    ((uint4*)Bws)[ci * 32 + k] = pk;
  }
}

// ---------------------------------------------------------------------------
// Main (byte-identical to R5/R7): template-unrolled steps, 512 threads =
// 8 waves, 1 row-tile/wave, 256 rows/block, 3 blocks/CU. ~9.4 us (HBM floor).
// ---------------------------------------------------------------------------
union AF8 { unsigned u[4]; f16x8 v; };

template<int S>
__device__ inline void gstep(const f16x8* __restrict__ Bf, int lane, int h,
                             unsigned sel, const u32x16& xu, f32x16& acc)
{
  f16x8 b = Bf[(S << 6) + lane];
  AF8 a;
  if constexpr (S < 40){
    constexpr int p = stepDA(S) >> 1;
    constexpr int e = stepEA(S) >> 1;
    unsigned m = __builtin_amdgcn_perm(xu[p], xu[p], sel);
    a.u[0] = pkmulh2(m, xu[e + 0]);
    a.u[1] = pkmulh2(m, xu[e + 1]);
    a.u[2] = pkmulh2(m, xu[e + 2]);
    a.u[3] = pkmulh2(m, xu[e + 3]);
  } else {
    constexpr int ea = stepEA(S) >> 1;
    constexpr int eb = stepEB(S) >> 1;
    a.u[0] = h ? xu[eb + 0] : xu[ea + 0];
    a.u[1] = h ? xu[eb + 1] : xu[ea + 1];
    a.u[2] = h ? xu[eb + 2] : xu[ea + 2];
    a.u[3] = h ? xu[eb + 3] : xu[ea + 3];
  }
  acc = __builtin_amdgcn_mfma_f32_32x32x16_f16(a.v, b, acc, 0, 0, 0);
}

template<int S>
__device__ inline void gsteps(const f16x8* __restrict__ Bf, int lane, int h,
                              unsigned sel, const u32x16& xu, f32x16& acc)
{
  if constexpr (S < NSTEP){
    gstep<S>(Bf, lane, h, sel, xu, acc);
    gsteps<S + 1>(Bf, lane, h, sel, xu, acc);
  }
}

__global__ __launch_bounds__(512, 4) void gmm_main(
    const float* __restrict__ X, const unsigned short* __restrict__ Bws,
    const float* __restrict__ cstg, float* __restrict__ out, int N)
{
  __shared__ uint4 ldsB[NSTEP * 64];   // 43008 B

  const int tid  = threadIdx.x;
  const int lane = tid & 63;
  const int wv   = tid >> 6;
  const int h    = lane >> 5;
  const int c32  = lane & 31;
  const int blockRow = blockIdx.x * 256;

  const uint4* Bg = (const uint4*)Bws;
  for (int i = tid; i < NSTEP * 64; i += 512) ldsB[i] = Bg[i];

  const unsigned sel = h ? 0x03020302u : 0x01000100u;

  const int rowi = blockRow + wv * 32 + c32;
  const int rowc = rowi < N ? rowi : N - 1;

  u32x16 xu;
  {
    const float4* xp = (const float4*)(X + (size_t)rowc * 32);
    #pragma unroll
    for (int q = 0; q < 8; ++q){
      float4 v = xp[q];
      xu[q*2+0] = pkrtz(v.x, v.y);
      xu[q*2+1] = pkrtz(v.z, v.w);
    }
  }
  const float cc = cstg[c32];
  __syncthreads();

  f32x16 acc;
  #pragma unroll
  for (int i = 0; i < 16; ++i) acc[i] = 0.f;

  gsteps<0>((const f16x8*)ldsB, lane, h, sel, xu, acc);

  float nll[16], mx[16];
  #pragma unroll
  for (int r = 0; r < 16; ++r){
    float nv = acc[r] + cc;
    nll[r] = nv; mx[r] = nv;
  }
  #pragma unroll
  for (int md = 1; md <= 16; md <<= 1){
    #pragma unroll
    for (int r = 0; r < 16; ++r)
      mx[r] = fmaxf(mx[r], __shfl_xor(mx[r], md));
  }
  const int rowBase = blockRow + wv * 32;
  #pragma unroll
  for (int r = 0; r < 16; ++r){
    int row = (r & 3) + 8 * (r >> 2) + 4 * h;
    int n = rowBase + row;
    if (n < N) out[(size_t)n * 32 + c32] = nll[r] * __builtin_amdgcn_rcpf(mx[r]);
  }
}

extern "C" void kernel_launch(void* const* d_in, const int* in_sizes, int n_in,
                              void* d_out, int out_size, void* d_ws, size_t ws_size,
                              hipStream_t stream)
{
  const float* X      = (const float*)d_in[0];
  const float* mus    = (const float*)d_in[1];
  const float* sigmas = (const float*)d_in[2];
  const float* phis   = (const float*)d_in[3];
  float* out = (float*)d_out;
  const int N = in_sizes[0] / 32;

  unsigned short* Bws = (unsigned short*)d_ws;
  float* cstw = (float*)((char*)d_ws + NCHUNK * 256 * 2);   // +43008 B

  gmm_prep<<<32, 64, 0, stream>>>(mus, sigmas, phis, Bws, cstw);

  const int nb = (N + 255) / 256;
  gmm_main<<<nb, 512, 0, stream>>>(X, Bws, cstw, out, N);
}